// Round 12
// baseline (263.736 us; speedup 1.0000x reference)
//
#include <hip/hip_runtime.h>

#define NN 50000
#define EE 800000
#define DIM 128
#define KK 256          // concat K: [agg(128) | self(128)]
#define OUTD 4
#define EPSV 1e-5f
#define OTS 132         // oT row stride (floats)
#define NB 196          // buckets = dst >> 8
#define SLOT 8192       // fixed pairs slots per bucket (mean 4082, sd 64)
#define ACHUNK 4096     // edges per passA block
#define NA 196          // ceil(EE / ACHUNK)

using short8v = __attribute__((ext_vector_type(8))) short;   // 8 bf16
using f32x4v  = __attribute__((ext_vector_type(4))) float;

__device__ __forceinline__ unsigned short f2bf(float f) {
    union { float f; unsigned u; } x; x.f = f;
    unsigned r = x.u + 0x7FFF + ((x.u >> 16) & 1);   // RNE
    return (unsigned short)(r >> 16);
}
__device__ __forceinline__ float bf2f(unsigned short u) {
    union { unsigned u; float f; } x; x.u = ((unsigned)u) << 16;
    return x.f;
}

// ---------------------------------------------------------------------------
// Feature buffers are QUARTER-MAJOR: [4][N][32] bf16. Slice p holds dims
// [32p, 32p+32) of every node: 3.2 MB per slice -> fits one XCD's 4MB L2.
// ---------------------------------------------------------------------------

// ---------------------------------------------------------------------------
// prepA: role-split grid (independent roles run concurrently).
//   blocks [0, 6250):        x f32 -> xqb bf16 (quarter-major)
//   blocks [6250, 6506):     Wt bf16 [128 j][256 k] both layers
//   blocks [6506, 6702):     passA bucket-scatter (bucketCursor pre-zeroed)
// pairs[b*SLOT + i] = (dst << 16) | src.
// ---------------------------------------------------------------------------
#define XB_BLK 6250
#define W_BLK  256
__global__ __launch_bounds__(256) void prepA_kernel(
    const float* __restrict__ x, ushort* __restrict__ xqb,
    const float* __restrict__ Wl0, const float* __restrict__ Wr0,
    const float* __restrict__ Wl1, const float* __restrict__ Wr1,
    ushort* __restrict__ Wt0, ushort* __restrict__ Wt1,
    const int* __restrict__ src, const int* __restrict__ dst,
    int* __restrict__ bucketCursor, unsigned* __restrict__ pairs)
{
    int b = blockIdx.x;
    int tid = threadIdx.x;
    if (b < XB_BLK) {
        int i = b * 256 + tid;                     // float4 idx < 1,600,000
        float4 v = ((const float4*)x)[i];
        ushort4 o;
        o.x = f2bf(v.x); o.y = f2bf(v.y); o.z = f2bf(v.z); o.w = f2bf(v.w);
        int node = i >> 5;
        int k = (i * 4) & 127;
        int p = k >> 5, off = k & 31;
        *(ushort4*)(xqb + ((size_t)p * NN + node) * 32 + off) = o;
        return;
    }
    if (b < XB_BLK + W_BLK) {
        int idx = (b - XB_BLK) * 256 + tid;        // 0..65535
        int which = idx >> 15;
        int j = (idx >> 8) & 127;
        int k = idx & 255;
        const float* Wl = which ? Wl1 : Wl0;
        const float* Wr = which ? Wr1 : Wr0;
        ushort* Wt = which ? Wt1 : Wt0;
        float v = (k < 128) ? Wl[k * DIM + j] : Wr[(k - 128) * DIM + j];
        Wt[j * KK + k] = f2bf(v);
        return;
    }

    // ---- passA role ----
    __shared__ int hist[256];
    __shared__ int scanb[256];
    __shared__ int exStart[256];
    __shared__ int cur2[256];
    __shared__ int gBase[256];
    __shared__ unsigned stage[ACHUNK];
    int ab = b - XB_BLK - W_BLK;
    int eBase = ab * ACHUNK;
    int total = min(ACHUNK, EE - eBase);

    hist[tid] = 0;
    __syncthreads();

    #pragma unroll
    for (int i = 0; i < 16; i++) {
        int idx = i * 256 + tid;
        if (idx < total) {
            int d = dst[eBase + idx];
            atomicAdd(&hist[d >> 8], 1);
        }
    }
    __syncthreads();
    int cntv = hist[tid];
    scanb[tid] = cntv;
    __syncthreads();
    #pragma unroll
    for (int off = 1; off < 256; off <<= 1) {
        int add = (tid >= off) ? scanb[tid - off] : 0;
        __syncthreads();
        scanb[tid] += add;
        __syncthreads();
    }
    int ex = scanb[tid] - cntv;
    exStart[tid] = ex;
    cur2[tid] = ex;
    if (tid < NB) gBase[tid] = (cntv > 0) ? atomicAdd(&bucketCursor[tid], cntv) : 0;
    __syncthreads();

    #pragma unroll
    for (int i = 0; i < 16; i++) {
        int idx = i * 256 + tid;
        if (idx < total) {
            int e = eBase + idx;
            int d = dst[e], s = src[e];
            int bb = d >> 8;
            int sp = atomicAdd(&cur2[bb], 1);
            stage[sp] = ((unsigned)d << 16) | (unsigned)s;
        }
    }
    __syncthreads();

    #pragma unroll
    for (int i = 0; i < 16; i++) {
        int idx = i * 256 + tid;
        if (idx < total) {
            unsigned v = stage[idx];
            int bb = v >> 24;
            int pos = gBase[bb] + (idx - exStart[bb]);
            if (pos < SLOT) pairs[(size_t)bb * SLOT + pos] = v;
        }
    }
}

// ---------------------------------------------------------------------------
// passB: one block per bucket. Count per local dst + LDS scan -> rowptr
// slice; then scatter colS (order within a dst is irrelevant: sum).
// ---------------------------------------------------------------------------
__global__ __launch_bounds__(256) void passB_kernel(
    const int* __restrict__ bucketCursor,
    const unsigned* __restrict__ pairs,
    int* __restrict__ rowptr, ushort* __restrict__ colS)
{
    __shared__ int bscan[256];
    __shared__ int cw[256];
    __shared__ int pre2[256];
    __shared__ unsigned val_lds[SLOT];
    int tid = threadIdx.x;
    int b = blockIdx.x;

    // bucket-base scan
    int c = (tid < NB) ? min(bucketCursor[tid], SLOT) : 0;
    bscan[tid] = c;
    __syncthreads();
    #pragma unroll
    for (int off = 1; off < 256; off <<= 1) {
        int add = (tid >= off) ? bscan[tid - off] : 0;
        __syncthreads();
        bscan[tid] += add;
        __syncthreads();
    }
    int myBase = b ? bscan[b - 1] : 0;
    int count  = bscan[b] - myBase;
    __syncthreads();

    cw[tid] = 0;
    __syncthreads();

    // pass 1: stage + count per local dst
    const unsigned* pb = pairs + (size_t)b * SLOT;
    for (int p = tid; p < count; p += 256) {
        unsigned v = pb[p];
        val_lds[p] = v;
        atomicAdd(&cw[(v >> 16) & 255], 1);
    }
    __syncthreads();
    int cnode = cw[tid];
    bscan[tid] = cnode;           // reuse for node scan
    __syncthreads();
    #pragma unroll
    for (int off = 1; off < 256; off <<= 1) {
        int add = (tid >= off) ? bscan[tid - off] : 0;
        __syncthreads();
        bscan[tid] += add;
        __syncthreads();
    }
    int preEx = bscan[tid] - cnode;
    pre2[tid] = preEx;
    int nodeBase = b << 8;
    if (nodeBase + tid < NN) rowptr[nodeBase + tid] = myBase + preEx;
    if (b == NB - 1 && tid == 0) rowptr[NN] = myBase + count;
    cw[tid] = 0;                  // fresh cursors for pass 2
    __syncthreads();

    // pass 2: scatter colS within bucket region
    for (int p = tid; p < count; p += 256) {
        unsigned v = val_lds[p];
        int dl = (v >> 16) & 255;
        int r = atomicAdd(&cw[dl], 1);
        colS[myBase + pre2[dl] + r] = (ushort)(v & 0xFFFF);
    }
}

// ---------------------------------------------------------------------------
// Fused layer. Gather: 4 quarter passes; pass p reads 64B/edge from the
// 3.2MB slice [p][N][32] (L2-resident per XCD). Thread t owns node t>>3,
// 8B sub-slice (t&7); 4-edge unroll. featB layout unchanged: dim d of agg
// at byte 2d ^ ((n&7)<<4); self at bytes [256,512).
// ---------------------------------------------------------------------------
template <int DO_HEAD>
__global__ __launch_bounds__(256) void sage_fused_kernel(
    const ushort* __restrict__ featG,     // bf16 quarter-major [4][N][32]
    const int* __restrict__ rowptr, const ushort* __restrict__ colS,
    const ushort* __restrict__ WtB,       // bf16 [128 j][256 k]
    const float* __restrict__ bl,
    const float* __restrict__ g, const float* __restrict__ beta,
    const float* __restrict__ Wh, const float* __restrict__ bh,
    void* __restrict__ outp)
{
    __shared__ __align__(16) char smem[32 * OTS * 4];   // 16.9 KB
    __shared__ float mu_s[32], ri_s[32];
    ushort* featB = (ushort*)smem;            // [32][256] bf16, swizzled
    float*  oT    = (float*)smem;             // overlays featB after MFMA
    #define OT(n, k) oT[(n) * OTS + (k)]

    int tid = threadIdx.x;
    int base = blockIdx.x * 32;
    int lane = tid & 63, w = tid >> 6;

    // ---- self-feature part: featB bytes [256,512), 16B chunks ----
    #pragma unroll
    for (int i = 0; i < 2; i++) {
        int idx = tid + i * 256;
        int n = idx >> 4, c = idx & 15;     // c: 16B chunk of the 256B row
        int node = base + n;
        short8v xv = {};
        if (node < NN) {
            int p = c >> 2;
            int off = (c & 3) * 8;
            xv = *(const short8v*)(featG + ((size_t)p * NN + node) * 32 + off);
        }
        int kb = (256 + c * 16) ^ ((n & 7) << 4);   // byte offset
        *(short8v*)(featB + n * KK + (kb >> 1)) = xv;
    }

    // ---- gather-mean: featB bytes [0,256), 4 quarter passes ----
    {
        int n = tid >> 3;          // node 0..31
        int sub = tid & 7;         // 8B sub-slice of the 64B quarter row
        int node = base + n;
        int beg = 0, end = 0;
        if (node < NN) { beg = rowptr[node]; end = rowptr[node + 1]; }
        float di = 1.0f / fmaxf((float)(end - beg), 1.0f);
        #pragma unroll 1
        for (int p = 0; p < 4; p++) {
            const ushort* xq = featG + (size_t)p * NN * 32 + sub * 4;
            float a0[4], a1[4], a2[4], a3[4];
            #pragma unroll
            for (int j = 0; j < 4; j++) { a0[j] = 0.f; a1[j] = 0.f; a2[j] = 0.f; a3[j] = 0.f; }
            int e = beg;
            for (; e + 3 < end; e += 4) {
                int s0 = colS[e], s1 = colS[e + 1], s2 = colS[e + 2], s3 = colS[e + 3];
                ushort4 v0 = *(const ushort4*)(xq + s0 * 32);
                ushort4 v1 = *(const ushort4*)(xq + s1 * 32);
                ushort4 v2 = *(const ushort4*)(xq + s2 * 32);
                ushort4 v3 = *(const ushort4*)(xq + s3 * 32);
                a0[0] += bf2f(v0.x); a0[1] += bf2f(v0.y); a0[2] += bf2f(v0.z); a0[3] += bf2f(v0.w);
                a1[0] += bf2f(v1.x); a1[1] += bf2f(v1.y); a1[2] += bf2f(v1.z); a1[3] += bf2f(v1.w);
                a2[0] += bf2f(v2.x); a2[1] += bf2f(v2.y); a2[2] += bf2f(v2.z); a2[3] += bf2f(v2.w);
                a3[0] += bf2f(v3.x); a3[1] += bf2f(v3.y); a3[2] += bf2f(v3.z); a3[3] += bf2f(v3.w);
            }
            for (; e < end; e++) {
                int s0 = colS[e];
                ushort4 v0 = *(const ushort4*)(xq + s0 * 32);
                a0[0] += bf2f(v0.x); a0[1] += bf2f(v0.y); a0[2] += bf2f(v0.z); a0[3] += bf2f(v0.w);
            }
            ushort4 o;
            float r0 = (a0[0] + a1[0] + a2[0] + a3[0]) * di;
            float r1 = (a0[1] + a1[1] + a2[1] + a3[1]) * di;
            float r2 = (a0[2] + a1[2] + a2[2] + a3[2]) * di;
            float r3 = (a0[3] + a1[3] + a2[3] + a3[3]) * di;
            o.x = f2bf(r0); o.y = f2bf(r1); o.z = f2bf(r2); o.w = f2bf(r3);
            int kb = (p * 64 + sub * 8) ^ ((n & 7) << 4);   // byte offset
            *(ushort4*)(featB + n * KK + (kb >> 1)) = o;
        }
    }
    __syncthreads();

    // ---- MFMA: C[32][128] = featB[32][256] x W[256][128] ----
    int l15 = lane & 15, q = lane >> 4;
    f32x4v acc00 = {}, acc01 = {}, acc10 = {}, acc11 = {};
    const ushort* wbase = WtB + (size_t)(w * 32) * KK;
    int n0 = l15, n1 = 16 + l15;
    int sw = (l15 & 7) << 4;
    #pragma unroll
    for (int ks = 0; ks < 8; ks++) {
        int kbA = ks * 64 + q * 16;                  // byte offset
        short8v a0 = *(const short8v*)(featB + n0 * KK + (((kbA) ^ sw) >> 1));
        short8v a1 = *(const short8v*)(featB + n1 * KK + (((kbA) ^ sw) >> 1));
        int koff = ks * 32 + q * 8;
        short8v b0 = *(const short8v*)(wbase + (size_t)l15 * KK + koff);
        short8v b1 = *(const short8v*)(wbase + (size_t)(16 + l15) * KK + koff);
        acc00 = __builtin_amdgcn_mfma_f32_16x16x32_bf16(a0, b0, acc00, 0, 0, 0);
        acc01 = __builtin_amdgcn_mfma_f32_16x16x32_bf16(a0, b1, acc01, 0, 0, 0);
        acc10 = __builtin_amdgcn_mfma_f32_16x16x32_bf16(a1, b0, acc10, 0, 0, 0);
        acc11 = __builtin_amdgcn_mfma_f32_16x16x32_bf16(a1, b1, acc11, 0, 0, 0);
    }
    __syncthreads();   // all featB reads done before oT overlays it

    // D layout: col = lane&15, row = (lane>>4)*4 + r
    {
        int c0 = w * 32 + l15, c1 = c0 + 16;
        float bl0v = bl[c0], bl1v = bl[c1];
        #pragma unroll
        for (int r = 0; r < 4; r++) {
            int r0 = q * 4 + r, r1 = 16 + q * 4 + r;
            OT(r0, c0) = acc00[r] + bl0v;
            OT(r0, c1) = acc01[r] + bl1v;
            OT(r1, c0) = acc10[r] + bl0v;
            OT(r1, c1) = acc11[r] + bl1v;
        }
    }
    __syncthreads();

    // ---- LayerNorm stats (f32): 8 threads per node ----
    {
        int n = tid >> 3, l = tid & 7;
        float s = 0.f, s2 = 0.f;
        #pragma unroll
        for (int kk = 0; kk < 16; kk++) {
            float v = OT(n, l * 16 + kk);
            s += v; s2 += v * v;
        }
        #pragma unroll
        for (int off = 4; off; off >>= 1) {
            s  += __shfl_down(s, off, 8);
            s2 += __shfl_down(s2, off, 8);
        }
        if (l == 0) {
            float mu = s * (1.0f / DIM);
            float var = s2 * (1.0f / DIM) - mu * mu;
            mu_s[n] = mu;
            ri_s[n] = rsqrtf(fmaxf(var, 0.f) + EPSV);
        }
    }
    __syncthreads();

    if (!DO_HEAD) {
        // h output in quarter-major [4][N][32]
        ushort* hout = (ushort*)outp;
        #pragma unroll
        for (int i = 0; i < 16; i++) {
            int idx = tid + i * 256;
            int n = idx >> 7, k = idx & 127;
            int node = base + n;
            if (node < NN) {
                float v = (OT(n, k) - mu_s[n]) * ri_s[n] * g[k] + beta[k];
                hout[((size_t)(k >> 5) * NN + node) * 32 + (k & 31)] = f2bf(fmaxf(v, 0.f));
            }
        }
    } else {
        float* fout = (float*)outp;
        float vals[16];
        #pragma unroll
        for (int i = 0; i < 16; i++) {
            int idx = tid + i * 256;
            int n = idx >> 7, k = idx & 127;
            float v = (OT(n, k) - mu_s[n]) * ri_s[n] * g[k] + beta[k];
            vals[i] = fmaxf(v, 0.f);
        }
        __syncthreads();
        #pragma unroll
        for (int i = 0; i < 16; i++) {
            int idx = tid + i * 256;
            int n = idx >> 7, k = idx & 127;
            OT(n, k) = vals[i];
        }
        __syncthreads();
        if (tid < 128) {
            int n = tid >> 2, o = tid & 3;
            int node = base + n;
            if (node < NN) {
                float s = bh[o];
                for (int k = 0; k < DIM; k++) s += OT(n, k) * Wh[k * OUTD + o];
                fout[(size_t)node * OUTD + o] = s;
            }
        }
    }
    #undef OT
}

extern "C" void kernel_launch(void* const* d_in, const int* in_sizes, int n_in,
                              void* d_out, int out_size, void* d_ws, size_t ws_size,
                              hipStream_t stream)
{
    const float* x    = (const float*)d_in[0];
    const int*   ei   = (const int*)d_in[1];   // [2, E] int32
    const float* Wl0  = (const float*)d_in[2];
    const float* bl0  = (const float*)d_in[3];
    const float* Wr0  = (const float*)d_in[4];
    const float* Wl1  = (const float*)d_in[5];
    const float* bl1  = (const float*)d_in[6];
    const float* Wr1  = (const float*)d_in[7];
    const float* g0   = (const float*)d_in[8];
    const float* be0  = (const float*)d_in[9];
    const float* g1   = (const float*)d_in[10];
    const float* be1  = (const float*)d_in[11];
    const float* Wh   = (const float*)d_in[12];
    const float* bh   = (const float*)d_in[13];
    float* out = (float*)d_out;

    const int* srcI = ei;
    const int* dstI = ei + EE;

    // ws layout (16B-aligned): xqb | h | Wt0 | Wt1 | rowptr | bucketCursor | pairs | colS
    char* p = (char*)d_ws;
    ushort*   xqb    = (ushort*)p;    p += (size_t)NN * DIM * 2;        // 12.8 MB
    ushort*   h      = (ushort*)p;    p += (size_t)NN * DIM * 2;        // 12.8 MB
    ushort*   Wt0    = (ushort*)p;    p += DIM * KK * 2;                // 64 KB
    ushort*   Wt1    = (ushort*)p;    p += DIM * KK * 2;                // 64 KB
    int*      rowptr = (int*)p;       p += 50016 * 4;                   // N+1, padded
    int*      bucketCursor = (int*)p; p += 256 * 4;
    unsigned* pairs  = (unsigned*)p;  p += (size_t)NB * SLOT * 4;       // 6.4 MB
    ushort*   colS   = (ushort*)p;    p += (size_t)EE * 2;              // 1.6 MB

    hipMemsetAsync(bucketCursor, 0, 256 * sizeof(int), stream);
    prepA_kernel<<<XB_BLK + W_BLK + NA, 256, 0, stream>>>(
        x, xqb, Wl0, Wr0, Wl1, Wr1, Wt0, Wt1, srcI, dstI, bucketCursor, pairs);
    passB_kernel<<<NB, 256, 0, stream>>>(bucketCursor, pairs, rowptr, colS);

    const int blocks = (NN + 31) / 32;
    sage_fused_kernel<0><<<blocks, 256, 0, stream>>>(
        xqb, rowptr, colS, Wt0, bl0, g0, be0, nullptr, nullptr, (void*)h);
    sage_fused_kernel<1><<<blocks, 256, 0, stream>>>(
        h, rowptr, colS, Wt1, bl1, g1, be1, Wh, bh, (void*)out);
}

// Round 13
// 214.836 us; speedup vs baseline: 1.2276x; 1.2276x over previous
//
#include <hip/hip_runtime.h>

#define NN 50000
#define EE 800000
#define DIM 128
#define KK 256          // concat K: [agg(128) | self(128)]
#define OUTD 4
#define EPSV 1e-5f
#define OTS 132         // oT row stride (floats)
#define NB 196          // buckets = dst >> 8
#define SLOT 8192       // fixed pairs slots per bucket (mean 4082, sd 64)
#define ACHUNK 4096     // edges per passA block
#define NA 196          // ceil(EE / ACHUNK)
#define ECAP 2048       // LDS colS stage capacity (block mean 512, sd 23)

using short8v = __attribute__((ext_vector_type(8))) short;   // 8 bf16
using f32x4v  = __attribute__((ext_vector_type(4))) float;

__device__ __forceinline__ unsigned short f2bf(float f) {
    union { float f; unsigned u; } x; x.f = f;
    unsigned r = x.u + 0x7FFF + ((x.u >> 16) & 1);   // RNE
    return (unsigned short)(r >> 16);
}
__device__ __forceinline__ float bf2f(unsigned short u) {
    union { unsigned u; float f; } x; x.u = ((unsigned)u) << 16;
    return x.f;
}

// ---------------------------------------------------------------------------
// Feature buffers QUARTER-MAJOR: [4][N][32] bf16; slice = 3.2MB < 4MB L2/XCD.
// ---------------------------------------------------------------------------

#define XB_BLK 6250
#define W_BLK  256
__global__ __launch_bounds__(256) void prepA_kernel(
    const float* __restrict__ x, ushort* __restrict__ xqb,
    const float* __restrict__ Wl0, const float* __restrict__ Wr0,
    const float* __restrict__ Wl1, const float* __restrict__ Wr1,
    ushort* __restrict__ Wt0, ushort* __restrict__ Wt1,
    const int* __restrict__ src, const int* __restrict__ dst,
    int* __restrict__ bucketCursor, unsigned* __restrict__ pairs)
{
    int b = blockIdx.x;
    int tid = threadIdx.x;
    if (b < XB_BLK) {
        int i = b * 256 + tid;                     // float4 idx < 1,600,000
        float4 v = ((const float4*)x)[i];
        ushort4 o;
        o.x = f2bf(v.x); o.y = f2bf(v.y); o.z = f2bf(v.z); o.w = f2bf(v.w);
        int node = i >> 5;
        int k = (i * 4) & 127;
        int p = k >> 5, off = k & 31;
        *(ushort4*)(xqb + ((size_t)p * NN + node) * 32 + off) = o;
        return;
    }
    if (b < XB_BLK + W_BLK) {
        int idx = (b - XB_BLK) * 256 + tid;        // 0..65535
        int which = idx >> 15;
        int j = (idx >> 8) & 127;
        int k = idx & 255;
        const float* Wl = which ? Wl1 : Wl0;
        const float* Wr = which ? Wr1 : Wr0;
        ushort* Wt = which ? Wt1 : Wt0;
        float v = (k < 128) ? Wl[k * DIM + j] : Wr[(k - 128) * DIM + j];
        Wt[j * KK + k] = f2bf(v);
        return;
    }

    // ---- passA role ----
    __shared__ int hist[256];
    __shared__ int scanb[256];
    __shared__ int exStart[256];
    __shared__ int cur2[256];
    __shared__ int gBase[256];
    __shared__ unsigned stage[ACHUNK];
    int ab = b - XB_BLK - W_BLK;
    int eBase = ab * ACHUNK;
    int total = min(ACHUNK, EE - eBase);

    hist[tid] = 0;
    __syncthreads();

    #pragma unroll
    for (int i = 0; i < 16; i++) {
        int idx = i * 256 + tid;
        if (idx < total) {
            int d = dst[eBase + idx];
            atomicAdd(&hist[d >> 8], 1);
        }
    }
    __syncthreads();
    int cntv = hist[tid];
    scanb[tid] = cntv;
    __syncthreads();
    #pragma unroll
    for (int off = 1; off < 256; off <<= 1) {
        int add = (tid >= off) ? scanb[tid - off] : 0;
        __syncthreads();
        scanb[tid] += add;
        __syncthreads();
    }
    int ex = scanb[tid] - cntv;
    exStart[tid] = ex;
    cur2[tid] = ex;
    if (tid < NB) gBase[tid] = (cntv > 0) ? atomicAdd(&bucketCursor[tid], cntv) : 0;
    __syncthreads();

    #pragma unroll
    for (int i = 0; i < 16; i++) {
        int idx = i * 256 + tid;
        if (idx < total) {
            int e = eBase + idx;
            int d = dst[e], s = src[e];
            int bb = d >> 8;
            int sp = atomicAdd(&cur2[bb], 1);
            stage[sp] = ((unsigned)d << 16) | (unsigned)s;
        }
    }
    __syncthreads();

    #pragma unroll
    for (int i = 0; i < 16; i++) {
        int idx = i * 256 + tid;
        if (idx < total) {
            unsigned v = stage[idx];
            int bb = v >> 24;
            int pos = gBase[bb] + (idx - exStart[bb]);
            if (pos < SLOT) pairs[(size_t)bb * SLOT + pos] = v;
        }
    }
}

// ---------------------------------------------------------------------------
// passB: one block per bucket -> rowptr slice + colS scatter (bucket-local).
// ---------------------------------------------------------------------------
__global__ __launch_bounds__(256) void passB_kernel(
    const int* __restrict__ bucketCursor,
    const unsigned* __restrict__ pairs,
    int* __restrict__ rowptr, ushort* __restrict__ colS)
{
    __shared__ int bscan[256];
    __shared__ int cw[256];
    __shared__ int pre2[256];
    __shared__ unsigned val_lds[SLOT];
    int tid = threadIdx.x;
    int b = blockIdx.x;

    int c = (tid < NB) ? min(bucketCursor[tid], SLOT) : 0;
    bscan[tid] = c;
    __syncthreads();
    #pragma unroll
    for (int off = 1; off < 256; off <<= 1) {
        int add = (tid >= off) ? bscan[tid - off] : 0;
        __syncthreads();
        bscan[tid] += add;
        __syncthreads();
    }
    int myBase = b ? bscan[b - 1] : 0;
    int count  = bscan[b] - myBase;
    __syncthreads();

    cw[tid] = 0;
    __syncthreads();

    const unsigned* pb = pairs + (size_t)b * SLOT;
    for (int p = tid; p < count; p += 256) {
        unsigned v = pb[p];
        val_lds[p] = v;
        atomicAdd(&cw[(v >> 16) & 255], 1);
    }
    __syncthreads();
    int cnode = cw[tid];
    bscan[tid] = cnode;
    __syncthreads();
    #pragma unroll
    for (int off = 1; off < 256; off <<= 1) {
        int add = (tid >= off) ? bscan[tid - off] : 0;
        __syncthreads();
        bscan[tid] += add;
        __syncthreads();
    }
    int preEx = bscan[tid] - cnode;
    pre2[tid] = preEx;
    int nodeBase = b << 8;
    if (nodeBase + tid < NN) rowptr[nodeBase + tid] = myBase + preEx;
    if (b == NB - 1 && tid == 0) rowptr[NN] = myBase + count;
    cw[tid] = 0;
    __syncthreads();

    for (int p = tid; p < count; p += 256) {
        unsigned v = val_lds[p];
        int dl = (v >> 16) & 255;
        int r = atomicAdd(&cw[dl], 1);
        colS[myBase + pre2[dl] + r] = (ushort)(v & 0xFFFF);
    }
}

// ---------------------------------------------------------------------------
// Fused layer. Gather: 4 quarter passes over L2-resident 3.2MB slices.
// Per node: 8 threads = 4 chunk-owners (16B each) x 2 edge parities;
// 2-deep unroll => 16x16B loads per edge-row TOTAL (same as r6 count).
// Block's colS range is contiguous (bucket-sorted CSR) -> staged in LDS once.
// ---------------------------------------------------------------------------
template <int DO_HEAD>
__global__ __launch_bounds__(256) void sage_fused_kernel(
    const ushort* __restrict__ featG,     // bf16 quarter-major [4][N][32]
    const int* __restrict__ rowptr, const ushort* __restrict__ colS,
    const ushort* __restrict__ WtB,       // bf16 [128 j][256 k]
    const float* __restrict__ bl,
    const float* __restrict__ g, const float* __restrict__ beta,
    const float* __restrict__ Wh, const float* __restrict__ bh,
    void* __restrict__ outp)
{
    __shared__ __align__(16) char smem[32 * OTS * 4];   // 16.9 KB
    __shared__ float mu_s[32], ri_s[32];
    __shared__ ushort colLds[ECAP];                     // 4 KB
    ushort* featB = (ushort*)smem;            // [32][256] bf16, swizzled
    float*  oT    = (float*)smem;             // overlays featB after MFMA
    #define OT(n, k) oT[(n) * OTS + (k)]

    int tid = threadIdx.x;
    int base = blockIdx.x * 32;
    int lane = tid & 63, w = tid >> 6;

    // ---- block edge range -> LDS stage (contiguous in colS) ----
    int beg0 = rowptr[base];
    int end0 = rowptr[min(base + 32, NN)];
    int cnt = end0 - beg0;
    for (int i = tid; i < cnt && i < ECAP; i += 256) colLds[i] = colS[beg0 + i];

    // ---- self-feature part: featB bytes [256,512), 16B chunks ----
    #pragma unroll
    for (int i = 0; i < 2; i++) {
        int idx = tid + i * 256;
        int n = idx >> 4, c = idx & 15;     // c: 16B chunk of the 256B row
        int node = base + n;
        short8v xv = {};
        if (node < NN) {
            int p = c >> 2;
            int off = (c & 3) * 8;
            xv = *(const short8v*)(featG + ((size_t)p * NN + node) * 32 + off);
        }
        int kb = (256 + c * 16) ^ ((n & 7) << 4);   // byte offset
        *(short8v*)(featB + n * KK + (kb >> 1)) = xv;
    }
    __syncthreads();   // colLds visible to all

    // ---- gather-mean: featB bytes [0,256), 4 quarter passes ----
    {
        int n = tid >> 3;          // node 0..31
        int sub = tid & 7;
        int chunk = sub >> 1;      // 16B chunk of the 64B quarter row
        int par = sub & 1;         // edge parity
        int node = base + n;
        int nb = 0, ne = 0;
        if (node < NN) { nb = rowptr[node]; ne = rowptr[node + 1]; }
        float di = 1.0f / fmaxf((float)(ne - nb), 1.0f);
        int sw = (n & 7) << 4;

        if (cnt <= ECAP) {
            int begL = nb - beg0, endL = ne - beg0;
            #pragma unroll 1
            for (int p = 0; p < 4; p++) {
                const ushort* xq = featG + (size_t)p * NN * 32 + chunk * 8;
                float a0[8], a1[8];
                #pragma unroll
                for (int j = 0; j < 8; j++) { a0[j] = 0.f; a1[j] = 0.f; }
                int e = begL + par;
                for (; e + 2 < endL; e += 4) {
                    int s0 = colLds[e], s1 = colLds[e + 2];
                    short8v v0 = *(const short8v*)(xq + (size_t)s0 * 32);
                    short8v v1 = *(const short8v*)(xq + (size_t)s1 * 32);
                    #pragma unroll
                    for (int j = 0; j < 8; j++) {
                        a0[j] += bf2f((unsigned short)v0[j]);
                        a1[j] += bf2f((unsigned short)v1[j]);
                    }
                }
                if (e < endL) {
                    int s0 = colLds[e];
                    short8v v0 = *(const short8v*)(xq + (size_t)s0 * 32);
                    #pragma unroll
                    for (int j = 0; j < 8; j++) a0[j] += bf2f((unsigned short)v0[j]);
                }
                short8v o;
                #pragma unroll
                for (int j = 0; j < 8; j++) {
                    float t = a0[j] + a1[j];
                    t += __shfl_xor(t, 1, 64);
                    o[j] = (short)f2bf(t * di);
                }
                if (par == 0) {
                    int kb = (p * 64 + chunk * 16) ^ sw;
                    *(short8v*)(featB + n * KK + (kb >> 1)) = o;
                }
            }
        } else {
            // fallback (statistically never): global colS reads
            #pragma unroll 1
            for (int p = 0; p < 4; p++) {
                const ushort* xq = featG + (size_t)p * NN * 32 + chunk * 8;
                float a[8];
                #pragma unroll
                for (int j = 0; j < 8; j++) a[j] = 0.f;
                for (int e = nb + par; e < ne; e += 2) {
                    int s0 = colS[e];
                    short8v v0 = *(const short8v*)(xq + (size_t)s0 * 32);
                    #pragma unroll
                    for (int j = 0; j < 8; j++) a[j] += bf2f((unsigned short)v0[j]);
                }
                short8v o;
                #pragma unroll
                for (int j = 0; j < 8; j++) {
                    float t = a[j];
                    t += __shfl_xor(t, 1, 64);
                    o[j] = (short)f2bf(t * di);
                }
                if (par == 0) {
                    int kb = (p * 64 + chunk * 16) ^ sw;
                    *(short8v*)(featB + n * KK + (kb >> 1)) = o;
                }
            }
        }
    }
    __syncthreads();

    // ---- MFMA: C[32][128] = featB[32][256] x W[256][128] ----
    int l15 = lane & 15, q = lane >> 4;
    f32x4v acc00 = {}, acc01 = {}, acc10 = {}, acc11 = {};
    const ushort* wbase = WtB + (size_t)(w * 32) * KK;
    int n0 = l15, n1 = 16 + l15;
    int sw2 = (l15 & 7) << 4;
    #pragma unroll
    for (int ks = 0; ks < 8; ks++) {
        int kbA = ks * 64 + q * 16;                  // byte offset
        short8v a0 = *(const short8v*)(featB + n0 * KK + (((kbA) ^ sw2) >> 1));
        short8v a1 = *(const short8v*)(featB + n1 * KK + (((kbA) ^ sw2) >> 1));
        int koff = ks * 32 + q * 8;
        short8v b0 = *(const short8v*)(wbase + (size_t)l15 * KK + koff);
        short8v b1 = *(const short8v*)(wbase + (size_t)(16 + l15) * KK + koff);
        acc00 = __builtin_amdgcn_mfma_f32_16x16x32_bf16(a0, b0, acc00, 0, 0, 0);
        acc01 = __builtin_amdgcn_mfma_f32_16x16x32_bf16(a0, b1, acc01, 0, 0, 0);
        acc10 = __builtin_amdgcn_mfma_f32_16x16x32_bf16(a1, b0, acc10, 0, 0, 0);
        acc11 = __builtin_amdgcn_mfma_f32_16x16x32_bf16(a1, b1, acc11, 0, 0, 0);
    }
    __syncthreads();   // all featB reads done before oT overlays it

    // D layout: col = lane&15, row = (lane>>4)*4 + r
    {
        int c0 = w * 32 + l15, c1 = c0 + 16;
        float bl0v = bl[c0], bl1v = bl[c1];
        #pragma unroll
        for (int r = 0; r < 4; r++) {
            int r0 = q * 4 + r, r1 = 16 + q * 4 + r;
            OT(r0, c0) = acc00[r] + bl0v;
            OT(r0, c1) = acc01[r] + bl1v;
            OT(r1, c0) = acc10[r] + bl0v;
            OT(r1, c1) = acc11[r] + bl1v;
        }
    }
    __syncthreads();

    // ---- LayerNorm stats (f32): 8 threads per node ----
    {
        int n = tid >> 3, l = tid & 7;
        float s = 0.f, s2 = 0.f;
        #pragma unroll
        for (int kk = 0; kk < 16; kk++) {
            float v = OT(n, l * 16 + kk);
            s += v; s2 += v * v;
        }
        #pragma unroll
        for (int off = 4; off; off >>= 1) {
            s  += __shfl_down(s, off, 8);
            s2 += __shfl_down(s2, off, 8);
        }
        if (l == 0) {
            float mu = s * (1.0f / DIM);
            float var = s2 * (1.0f / DIM) - mu * mu;
            mu_s[n] = mu;
            ri_s[n] = rsqrtf(fmaxf(var, 0.f) + EPSV);
        }
    }
    __syncthreads();

    if (!DO_HEAD) {
        // h output in quarter-major [4][N][32]
        ushort* hout = (ushort*)outp;
        #pragma unroll
        for (int i = 0; i < 16; i++) {
            int idx = tid + i * 256;
            int n = idx >> 7, k = idx & 127;
            int node = base + n;
            if (node < NN) {
                float v = (OT(n, k) - mu_s[n]) * ri_s[n] * g[k] + beta[k];
                hout[((size_t)(k >> 5) * NN + node) * 32 + (k & 31)] = f2bf(fmaxf(v, 0.f));
            }
        }
    } else {
        float* fout = (float*)outp;
        float vals[16];
        #pragma unroll
        for (int i = 0; i < 16; i++) {
            int idx = tid + i * 256;
            int n = idx >> 7, k = idx & 127;
            float v = (OT(n, k) - mu_s[n]) * ri_s[n] * g[k] + beta[k];
            vals[i] = fmaxf(v, 0.f);
        }
        __syncthreads();
        #pragma unroll
        for (int i = 0; i < 16; i++) {
            int idx = tid + i * 256;
            int n = idx >> 7, k = idx & 127;
            OT(n, k) = vals[i];
        }
        __syncthreads();
        if (tid < 128) {
            int n = tid >> 2, o = tid & 3;
            int node = base + n;
            if (node < NN) {
                float s = bh[o];
                for (int k = 0; k < DIM; k++) s += OT(n, k) * Wh[k * OUTD + o];
                fout[(size_t)node * OUTD + o] = s;
            }
        }
    }
    #undef OT
}

extern "C" void kernel_launch(void* const* d_in, const int* in_sizes, int n_in,
                              void* d_out, int out_size, void* d_ws, size_t ws_size,
                              hipStream_t stream)
{
    const float* x    = (const float*)d_in[0];
    const int*   ei   = (const int*)d_in[1];   // [2, E] int32
    const float* Wl0  = (const float*)d_in[2];
    const float* bl0  = (const float*)d_in[3];
    const float* Wr0  = (const float*)d_in[4];
    const float* Wl1  = (const float*)d_in[5];
    const float* bl1  = (const float*)d_in[6];
    const float* Wr1  = (const float*)d_in[7];
    const float* g0   = (const float*)d_in[8];
    const float* be0  = (const float*)d_in[9];
    const float* g1   = (const float*)d_in[10];
    const float* be1  = (const float*)d_in[11];
    const float* Wh   = (const float*)d_in[12];
    const float* bh   = (const float*)d_in[13];
    float* out = (float*)d_out;

    const int* srcI = ei;
    const int* dstI = ei + EE;

    // ws layout (16B-aligned): xqb | h | Wt0 | Wt1 | rowptr | bucketCursor | pairs | colS
    char* p = (char*)d_ws;
    ushort*   xqb    = (ushort*)p;    p += (size_t)NN * DIM * 2;        // 12.8 MB
    ushort*   h      = (ushort*)p;    p += (size_t)NN * DIM * 2;        // 12.8 MB
    ushort*   Wt0    = (ushort*)p;    p += DIM * KK * 2;                // 64 KB
    ushort*   Wt1    = (ushort*)p;    p += DIM * KK * 2;                // 64 KB
    int*      rowptr = (int*)p;       p += 50016 * 4;                   // N+1, padded
    int*      bucketCursor = (int*)p; p += 256 * 4;
    unsigned* pairs  = (unsigned*)p;  p += (size_t)NB * SLOT * 4;       // 6.4 MB
    ushort*   colS   = (ushort*)p;    p += (size_t)EE * 2;              // 1.6 MB

    hipMemsetAsync(bucketCursor, 0, 256 * sizeof(int), stream);
    prepA_kernel<<<XB_BLK + W_BLK + NA, 256, 0, stream>>>(
        x, xqb, Wl0, Wr0, Wl1, Wr1, Wt0, Wt1, srcI, dstI, bucketCursor, pairs);
    passB_kernel<<<NB, 256, 0, stream>>>(bucketCursor, pairs, rowptr, colS);

    const int blocks = (NN + 31) / 32;
    sage_fused_kernel<0><<<blocks, 256, 0, stream>>>(
        xqb, rowptr, colS, Wt0, bl0, g0, be0, nullptr, nullptr, (void*)h);
    sage_fused_kernel<1><<<blocks, 256, 0, stream>>>(
        h, rowptr, colS, Wt1, bl1, g1, be1, Wh, bh, (void*)out);
}